// Round 20
// baseline (401.461 us; speedup 1.0000x reference)
//
#include <hip/hip_runtime.h>
#include <math.h>

#define DIM 384
#define NUM_HEADS 8
#define RES 14
#define RES2 7
#define NPOS 196
#define N2 49
#define DHEAD 64
#define NH_KD 128
#define DH 512
#define OUT_DIM 768
#define BATCH 512
#define SCALE_Q 0.25f
#define LOG2E 1.4426950408889634f
#define SCALE2 (SCALE_Q * LOG2E)

typedef unsigned short u16;
typedef short s16x8 __attribute__((ext_vector_type(8)));
typedef short s16x4 __attribute__((ext_vector_type(4)));
typedef float f32x4 __attribute__((ext_vector_type(4)));
typedef unsigned int u32x2 __attribute__((ext_vector_type(2)));

__device__ __forceinline__ float bf2f(u16 u) {
  union { unsigned int i; float f; } v; v.i = ((unsigned int)u) << 16; return v.f;
}
__device__ __forceinline__ u16 f2bf(float f) {
  union { unsigned int i; float f; } v; v.f = f;
  unsigned int r = v.i + 0x7fffu + ((v.i >> 16) & 1u);
  return (u16)(r >> 16);
}

// gelu exact-erf via A&S 7.1.26 poly (|err|<=1.5e-7; p(1)=1 so erf(0)=0 exactly)
__device__ __forceinline__ float gelu_f(float x) {
  float z = x * 0.70710678118f;
  float az = fabsf(z);
  float t = __builtin_amdgcn_rcpf(1.f + 0.3275911f * az);
  float p = ((((1.061405429f * t - 1.453152027f) * t + 1.421413741f) * t
              - 0.284496736f) * t + 0.254829592f) * t;
  float erfv = 1.f - p * __expf(-az * az);
  erfv = copysignf(erfv, z);
  return 0.5f * x * (1.f + erfv);
}

#define GLD16(gp, lp) __builtin_amdgcn_global_load_lds( \
    (const __attribute__((address_space(1))) void*)(gp), \
    (__attribute__((address_space(3))) void*)(lp), 16, 0, 0)

// ---------- fused prep: weight casts + bias gather (bias pre-scaled by log2e) ----------
__global__ __launch_bounds__(256) void k_prep(const float* __restrict__ kw, const float* __restrict__ vw,
                                              const float* __restrict__ qw, const float* __restrict__ pw,
                                              const float* __restrict__ ab, const int* __restrict__ idxs, int noff,
                                              u16* __restrict__ kwb, u16* __restrict__ vwb,
                                              u16* __restrict__ qwb, u16* __restrict__ pwb,
                                              float* __restrict__ bxp) {
  int i = blockIdx.x * 256 + threadIdx.x;
  const int e1 = NH_KD * DIM;                // 49152
  const int e2 = e1 + DH * DIM;              // 245760
  const int e3 = e2 + NH_KD * DIM;           // 294912
  const int e4 = e3 + OUT_DIM * DH;          // 688128
  const int e5 = e4 + NUM_HEADS * N2 * 256;  // 788480
  if (i < e1) kwb[i] = f2bf(kw[i]);
  else if (i < e2) vwb[i - e1] = f2bf(vw[i - e1]);
  else if (i < e3) qwb[i - e2] = f2bf(qw[i - e2]);
  else if (i < e4) pwb[i - e3] = f2bf(pw[i - e3]);
  else if (i < e5) {
    int j = i - e4;
    int f = j & 15, c = (j >> 4) & 15;
    int m = (j >> 8) % N2, h = j / (N2 * 256);
    int n = f * 16 + c;
    bxp[j] = (n < NPOS) ? ab[h * noff + idxs[m * NPOS + n]] * LOG2E : 0.f;
  }
}

// ---------- fused transpose + depthwise dwconv_q ----------
// tileT[196 pos][70 ch] u16 (r13-verified phases 2/3); r19 paired-channel phase 1.
__global__ __launch_bounds__(256, 5) void k_transpose_dwq(const float* __restrict__ x, u16* __restrict__ xt,
                                                          const float* __restrict__ qlw, const float* __restrict__ qlb,
                                                          u16* __restrict__ qlt) {
  int b = blockIdx.y, c0 = blockIdx.x * 64;
  __shared__ __align__(8) u16 tileT[196 * 70];   // 27,440 B
  __shared__ float wlds2[576];                   // [tap][64 ch]
  __shared__ float blds[64];
  int tid = threadIdx.x;
  const float* xb = x + (size_t)b * DIM * NPOS;

  // phase 1: 32 ch-pairs x 49 f32x4 chunks; both streams coalesced, packed b32 writes
  for (int idx = tid; idx < 32 * 49; idx += 256) {
    int chp = idx / 49, p4 = idx - chp * 49;
    const float* base = xb + (size_t)(c0 + 2 * chp) * NPOS + p4 * 4;
    f32x4 a  = *(const f32x4*)(base);
    f32x4 bv = *(const f32x4*)(base + NPOS);
#pragma unroll
    for (int j = 0; j < 4; j++) {
      uint pk = (uint)f2bf(a[j]) | ((uint)f2bf(bv[j]) << 16);
      *(uint*)&tileT[(p4 * 4 + j) * 70 + 2 * chp] = pk;
    }
  }
  for (int i = tid; i < 576; i += 256) {
    int c = i / 9, t = i % 9;
    wlds2[t * 64 + c] = qlw[(size_t)(c0 + c) * 9 + t];
  }
  if (tid < 64) blds[tid] = qlb[c0 + tid];
  __syncthreads();

  // phase 2: xbT write, 8 channels per lane, 16B vector stores
  u16* xtb = xt + (size_t)b * NPOS * DIM + c0;
  for (int idx = tid; idx < NPOS * 8; idx += 256) {
    int n = idx >> 3, g = (idx & 7) << 3;
    s16x8 val;
    ((uint*)&val)[0] = *(const uint*)&tileT[n * 70 + g];
    ((uint*)&val)[1] = *(const uint*)&tileT[n * 70 + g + 2];
    ((uint*)&val)[2] = *(const uint*)&tileT[n * 70 + g + 4];
    ((uint*)&val)[3] = *(const uint*)&tileT[n * 70 + g + 6];
    *(s16x8*)(xtb + (size_t)n * DIM + g) = val;
  }
  // phase 3: dwconv, 2 channels per lane, packed 4B stores
  u16* qb = qlt + (size_t)b * N2 * DIM + c0;
  for (int idx = tid; idx < N2 * 32; idx += 256) {
    int cp = idx & 31, n2 = idx >> 5;
    int c = cp << 1;
    int r = n2 / RES2, s = n2 % RES2;
    uint rv = *(const uint*)&tileT[((2 * r) * RES + 2 * s) * 70 + c];
    float a0 = blds[c]     + bf2f((u16)(rv & 0xffff));
    float a1 = blds[c + 1] + bf2f((u16)(rv >> 16));
#pragma unroll
    for (int dy = 0; dy < 3; dy++) {
      int ry = 2 * r - 1 + dy;
      if (ry < 0 || ry >= RES) continue;
#pragma unroll
      for (int dx = 0; dx < 3; dx++) {
        int sx = 2 * s - 1 + dx;
        if (sx < 0 || sx >= RES) continue;
        uint tv = *(const uint*)&tileT[(ry * RES + sx) * 70 + c];
        int t = dy * 3 + dx;
        a0 += wlds2[t * 64 + c]     * bf2f((u16)(tv & 0xffff));
        a1 += wlds2[t * 64 + c + 1] * bf2f((u16)(tv >> 16));
      }
    }
    uint outp = (uint)f2bf(a0) | ((uint)f2bf(a1) << 16);
    *(uint*)(qb + (size_t)n2 * DIM + c) = outp;
  }
}

// ---------- flattened GEMM: C = A[M][K] x B[N][K]^T, both K-contiguous bf16 ----------
// 128x128 tile, BK=64 (two 32-K halves, one barrier per 64-K), GLD16 staging both operands.
// Source pre-swizzle (m173/rule21): lane fetches global granule (l&3)^((l>>3)&3);
// frag reads un-swizzle with rg8 = ((l>>4)^((l>>1)&3))*8 -> conflict-free both sides.
// SPLN>0: out[(n/SPLN)*bstride + m*SPLN + n%SPLN] (ch=m), honors F32OUT.
// HBLK>0: head-blocked output [b][h=n>>4][pos=m%HBLK][n&15] (ch=n).
// NOTE (r10/r11): do NOT merge these GEMMs — L2 thrash. NOTE (r15): do NOT read A
// direct-from-global in-loop — scattered 16B reads stall the MFMA chain (87->128 us).
template <int SPLN, bool F32OUT, int HBLK>
__global__ __launch_bounds__(256) void k_gemm_flat(
    const u16* __restrict__ A, const u16* __restrict__ B, void* __restrict__ C,
    const float* __restrict__ cb, const float* __restrict__ bns, const float* __restrict__ bnt,
    int K, int NMT, int ldc, long bstride) {
  __shared__ __align__(16) u16 a_lds[2 * 128 * 32];
  __shared__ __align__(16) u16 b_lds[2 * 128 * 32];
  int nwg = gridDim.x, bx = blockIdx.x;
  int wg = ((nwg & 7) == 0) ? ((bx & 7) * (nwg >> 3) + (bx >> 3)) : bx;  // XCD-bijective
  int mt = wg % NMT, nt = wg / NMT;                                      // m fastest: j-tile shared on-XCD
  int m0 = mt * 128, n0 = nt * 128;
  int tid = threadIdx.x, w = tid >> 6, l = tid & 63;

  int srow = l >> 2;
  int scol = ((l & 3) ^ ((l >> 3) & 3)) * 8;   // pre-swizzled source granule
  const u16* asrc[2]; const u16* bsrc[2];
#pragma unroll
  for (int c = 0; c < 2; c++) {
    int chunk = w * 2 + c;
    asrc[c] = A + (size_t)(m0 + chunk * 16 + srow) * K + scol;
    bsrc[c] = B + (size_t)(n0 + chunk * 16 + srow) * K + scol;
  }
  char* adst = (char*)a_lds + (w * 2) * 1024 + l * 16;
  char* bdst = (char*)b_lds + (w * 2) * 1024 + l * 16;

  f32x4 acc[4][4];
#pragma unroll
  for (int i = 0; i < 4; i++)
#pragma unroll
    for (int j = 0; j < 4; j++) acc[i][j] = (f32x4){0.f, 0.f, 0.f, 0.f};

  int wm = w >> 1, wn = w & 1;
  int rg8 = ((l >> 4) ^ ((l >> 1) & 3)) * 8;   // un-swizzling read granule
  int arow = wm * 64 + (l & 15);
  int brow = wn * 64 + (l & 15);

  for (int kk = 0; kk < K; kk += 64) {
#pragma unroll
    for (int c = 0; c < 2; c++) {
      GLD16(asrc[c] + kk,      adst + c * 1024);
      GLD16(asrc[c] + kk + 32, adst + 8192 + c * 1024);
      GLD16(bsrc[c] + kk,      bdst + c * 1024);
      GLD16(bsrc[c] + kk + 32, bdst + 8192 + c * 1024);
    }
    __syncthreads();                 // compiler drains vmcnt before barrier
#pragma unroll
    for (int hf = 0; hf < 2; hf++) {
      const u16* ah = a_lds + hf * (128 * 32);
      const u16* bh = b_lds + hf * (128 * 32);
      s16x8 af[4], bf[4];
#pragma unroll
      for (int i = 0; i < 4; i++) {
        af[i] = *(const s16x8*)(&ah[(arow + i * 16) * 32 + rg8]);
        bf[i] = *(const s16x8*)(&bh[(brow + i * 16) * 32 + rg8]);
      }
#pragma unroll
      for (int i = 0; i < 4; i++)
#pragma unroll
        for (int j = 0; j < 4; j++)
          acc[i][j] = __builtin_amdgcn_mfma_f32_16x16x32_bf16(af[i], bf[j], acc[i][j], 0, 0, 0);
    }
    __syncthreads();
  }

  int ncol = l & 15, mq = (l >> 4) * 4;
#pragma unroll
  for (int i = 0; i < 4; i++) {
#pragma unroll
    for (int j = 0; j < 4; j++) {
      int n = n0 + wn * 64 + j * 16 + ncol;
#pragma unroll
      for (int r = 0; r < 4; r++) {
        int m = m0 + wm * 64 + i * 16 + mq + r;
        int ch = SPLN ? m : n;
        float val = acc[i][j][r] * bns[ch] + (cb[ch] * bns[ch] + bnt[ch]);
        size_t o;
        if (HBLK) {
          int bb = m / HBLK, pos = m - bb * HBLK;
          o = (((size_t)bb * NUM_HEADS + (n >> 4)) * HBLK + pos) * 16 + (n & 15);
        } else if (SPLN) {
          o = (size_t)(n / SPLN) * bstride + (size_t)m * SPLN + (n % SPLN);
        } else {
          o = (size_t)m * ldc + n;
        }
        if (F32OUT) ((float*)C)[o] = val;
        else        ((u16*)C)[o] = f2bf(val);
      }
    }
  }
}

// ---------- v_local = BN(dwconv_s2(v4) + b) -> vlT (bf16 [b][49][512]) ----------
__global__ __launch_bounds__(256, 6) void k_dwconv_v(const u16* __restrict__ v4, const float* __restrict__ w,
    const float* __restrict__ bias, const float* __restrict__ bns, const float* __restrict__ bnt,
    u16* __restrict__ vlt) {
  int b = blockIdx.y, ct = blockIdx.x;
  __shared__ __align__(8) u16 tile[64][196];
  int tid = threadIdx.x, wave = tid >> 6, lane = tid & 63;
  const u16* vbp = v4 + ((size_t)b * DH + ct * 64) * NPOS;
  for (int r = wave; r < 64; r += 4) {
    const u32x2* grow = (const u32x2*)(vbp + (size_t)r * NPOS);
    if (lane < 49) ((u32x2*)&tile[r][0])[lane] = grow[lane];
  }
  __syncthreads();
  for (int idx = tid; idx < 64 * N2; idx += 256) {
    int cl = idx & 63, n2 = idx >> 6;
    int ch = ct * 64 + cl;
    int r = n2 / RES2, s = n2 % RES2;
    float acc = bias[ch];
#pragma unroll
    for (int dy = 0; dy < 3; dy++) {
      int ry = 2 * r - 1 + dy;
      if (ry < 0 || ry >= RES) continue;
#pragma unroll
      for (int dx = 0; dx < 3; dx++) {
        int sx = 2 * s - 1 + dx;
        if (sx < 0 || sx >= RES) continue;
        acc += w[ch * 9 + dy * 3 + dx] * bf2f(tile[cl][ry * RES + sx]);
      }
    }
    vlt[((size_t)b * N2 + n2) * DH + ch] = f2bf(acc * bns[ch] + bnt[ch]);
  }
}

// ---------- MFMA attention per (b,h), LDS = p_lds only (29.7 KB, 5 blocks/CU) ----------
// Q/K in head-blocked layouts ([b][h][pos][16]) -> wave frag loads are one contiguous
// 512B block. exp2-folded softmax (scale/bias pre-multiplied by log2e).
// V direct from v4 ([b][512][196] = B-operand rows) as 2x8B. o_lds overlaps p_lds.
__global__ __launch_bounds__(256, 5) void k_attn_mfma(const u16* __restrict__ qTh, const u16* __restrict__ kTh,
    const u16* __restrict__ v4, const float* __restrict__ bxp, const u16* __restrict__ vlT,
    u16* __restrict__ gT) {
  int h = blockIdx.x, b = blockIdx.y;
  __shared__ __align__(16) u16 p_lds[64 * 232];   // 29,696 B
  float* o_lds = (float*)p_lds;                   // overlap (barrier-protected)
  int tid = threadIdx.x, w = tid >> 6, l = tid & 63;
  int part = l >> 4, row16 = l & 15;
  int mbase = w * 16 + part * 4;
  int ncol = l & 15;

  for (int idx = tid; idx < 64 * 8; idx += 256)
    ((uint*)&p_lds[(idx >> 3) * 232])[104 + (idx & 7)] = 0;

  // Q frag: qTh[b][h][pos][16], contiguous 512B per wave-frag (rows >=49 -> masked garbage)
  const u16* qbase = qTh + ((size_t)(b * NUM_HEADS + h) * N2) * 16;
  s16x8 af = (s16x8){0, 0, 0, 0, 0, 0, 0, 0};
  if (part < 2)
    af = *(const s16x8*)(qbase + (w * 16 + row16) * 16 + part * 8);

  // K frags: kTh[b][h][pos][16] (rows >=196 -> masked garbage)
  const u16* kbase = kTh + ((size_t)(b * NUM_HEADS + h) * NPOS) * 16 + part * 8;
  f32x4 s[13];
#pragma unroll
  for (int f = 0; f < 13; f++) {
    s16x8 bf = (s16x8){0, 0, 0, 0, 0, 0, 0, 0};
    if (part < 2)
      bf = *(const s16x8*)(kbase + (size_t)(f * 16 + row16) * 16);
    s[f] = __builtin_amdgcn_mfma_f32_16x16x32_bf16(af, bf, (f32x4){0.f, 0.f, 0.f, 0.f}, 0, 0, 0);
  }

  const u16* vbase = v4 + ((size_t)b * DH + h * DHEAD) * NPOS;
  int vd = l & 15, vq8 = part * 8;
  auto VLOAD = [&](int f, int kk) {
    const u16* p = vbase + (size_t)(f * 16 + vd) * NPOS + kk + vq8;
    s16x8 r;
    ((u32x2*)&r)[0] = *(const u32x2*)(p);
    ((u32x2*)&r)[1] = *(const u32x2*)(p + 4);
    return r;
  };
  s16x8 vb0[4];
#pragma unroll
  for (int f = 0; f < 4; f++) vb0[f] = VLOAD(f, 0);

  // scale+bias (log2e-folded) + mask
#pragma unroll
  for (int q = 0; q < 4; q++) {
    f32x4 bqr[4];
#pragma unroll
    for (int r = 0; r < 4; r++) {
      int mm = mbase + r; if (mm > N2 - 1) mm = N2 - 1;
      bqr[r] = *(const f32x4*)(bxp + (((size_t)h * N2 + mm) * 16 + ncol) * 16 + q * 4);
    }
#pragma unroll
    for (int ff = 0; ff < 4; ff++) {
      int f = q * 4 + ff;
      if (f < 13) {
        int n = f * 16 + ncol;
#pragma unroll
        for (int r = 0; r < 4; r++) {
          int m = mbase + r;
          s[f][r] = (m < N2 && n < NPOS) ? s[f][r] * SCALE2 + bqr[r][ff] : -1e30f;
        }
      }
    }
  }
  // softmax in base-2: rows live in 16-lane groups -> shfl_xor 1,2,4,8
#pragma unroll
  for (int r = 0; r < 4; r++) {
    float mx = s[0][r];
#pragma unroll
    for (int f = 1; f < 13; f++) mx = fmaxf(mx, s[f][r]);
    mx = fmaxf(mx, __shfl_xor(mx, 1)); mx = fmaxf(mx, __shfl_xor(mx, 2));
    mx = fmaxf(mx, __shfl_xor(mx, 4)); mx = fmaxf(mx, __shfl_xor(mx, 8));
    float sum = 0.f;
#pragma unroll
    for (int f = 0; f < 13; f++) { s[f][r] = exp2f(s[f][r] - mx); sum += s[f][r]; }
    sum += __shfl_xor(sum, 1); sum += __shfl_xor(sum, 2);
    sum += __shfl_xor(sum, 4); sum += __shfl_xor(sum, 8);
    float inv = 1.f / sum;
#pragma unroll
    for (int f = 0; f < 13; f++) s[f][r] *= inv;
  }
#pragma unroll
  for (int f = 0; f < 13; f++) {
    int n = f * 16 + ncol;
#pragma unroll
    for (int r = 0; r < 4; r++)
      p_lds[(mbase + r) * 232 + n] = f2bf(s[f][r]);
  }
  __syncthreads();

  f32x4 o[4];
#pragma unroll
  for (int f = 0; f < 4; f++) o[f] = (f32x4){0.f, 0.f, 0.f, 0.f};
#pragma unroll
  for (int t = 0; t < 7; t++) {
    int kk = t * 32;
    s16x8 vn[4];
    if (t < 6) {
#pragma unroll
      for (int f = 0; f < 4; f++) vn[f] = VLOAD(f, kk + 32);
    }
    s16x8 pa = *(const s16x8*)(&p_lds[(w * 16 + row16) * 232 + kk + part * 8]);
#pragma unroll
    for (int f = 0; f < 4; f++)
      o[f] = __builtin_amdgcn_mfma_f32_16x16x32_bf16(pa, vb0[f], o[f], 0, 0, 0);
    if (t < 6) {
#pragma unroll
      for (int f = 0; f < 4; f++) vb0[f] = vn[f];
    }
  }
  __syncthreads();

#pragma unroll
  for (int f = 0; f < 4; f++)
#pragma unroll
    for (int r = 0; r < 4; r++) {
      int m = mbase + r;
      if (m < N2) o_lds[m * 68 + f * 16 + ncol] = o[f][r];
    }
  __syncthreads();

  for (int idx = tid; idx < N2 * 16; idx += 256) {
    int row = idx >> 4, c4 = (idx & 15) << 2;
    f32x4 ov = *(const f32x4*)(&o_lds[row * 68 + c4]);
    size_t go = ((size_t)b * N2 + row) * DH + h * DHEAD + c4;
    s16x4 vv = *(const s16x4*)(vlT + go);
    s16x4 outv;
#pragma unroll
    for (int e = 0; e < 4; e++) {
      float xv = ov[e] + bf2f((u16)vv[e]);
      outv[e] = (short)f2bf(gelu_f(xv));
    }
    *(s16x4*)(gT + go) = outv;
  }
}

extern "C" void kernel_launch(void* const* d_in, const int* in_sizes, int n_in,
                              void* d_out, int out_size, void* d_ws, size_t ws_size,
                              hipStream_t stream) {
  const float* x   = (const float*)d_in[0];
  const float* qlw = (const float*)d_in[1];
  const float* qlb = (const float*)d_in[2];
  const float* qpw = (const float*)d_in[3];
  const float* qpb = (const float*)d_in[4];
  const float* qbs = (const float*)d_in[5];
  const float* qbt = (const float*)d_in[6];
  const float* kw  = (const float*)d_in[7];
  const float* kb  = (const float*)d_in[8];
  const float* kbs = (const float*)d_in[9];
  const float* kbt = (const float*)d_in[10];
  const float* vw  = (const float*)d_in[11];
  const float* vb  = (const float*)d_in[12];
  const float* vbs = (const float*)d_in[13];
  const float* vbt = (const float*)d_in[14];
  const float* vlw = (const float*)d_in[15];
  const float* vlb = (const float*)d_in[16];
  const float* vls = (const float*)d_in[17];
  const float* vlt_in = (const float*)d_in[18];
  const float* pw  = (const float*)d_in[19];
  const float* pb  = (const float*)d_in[20];
  const float* pbs = (const float*)d_in[21];
  const float* pbt = (const float*)d_in[22];
  const float* ab  = (const float*)d_in[23];
  const int*   bidx = (const int*)d_in[24];
  int noff = in_sizes[23] / NUM_HEADS;

  char* ws = (char*)d_ws;
  size_t off = 0;
  auto alloc = [&](size_t bytes) { char* p = ws + off; off += (bytes + 255) & ~(size_t)255; return p; };
  u16* xbT = (u16*)alloc((size_t)BATCH * NPOS * DIM * 2);      // 77.1 MB (aliased by gT later)
  u16* kTm = (u16*)alloc((size_t)BATCH * NPOS * NH_KD * 2);    // 25.7 MB (head-blocked [b][h][196][16])
  u16* qlT = (u16*)alloc((size_t)BATCH * N2 * DIM * 2);        // 19.3 MB
  u16* qTm = (u16*)alloc((size_t)BATCH * N2 * NH_KD * 2);      //  6.4 MB (head-blocked [b][h][49][16])
  u16* v4m = (u16*)alloc((size_t)BATCH * DH * NPOS * 2);       // 102.8 MB
  u16* vlTm = (u16*)alloc((size_t)BATCH * N2 * DH * 2);        // 25.7 MB  (absorbs attn's OOB V reads)
  float* bxp = (float*)alloc((size_t)NUM_HEADS * N2 * 16 * 16 * 4);  // 0.8 MB
  u16* kwb = (u16*)alloc((size_t)NH_KD * DIM * 2);
  u16* vwb = (u16*)alloc((size_t)DH * DIM * 2);
  u16* qwb = (u16*)alloc((size_t)NH_KD * DIM * 2);
  u16* pwb = (u16*)alloc((size_t)OUT_DIM * DH * 2);
  u16* gTm = xbT;  // alias: all xbT readers complete before k_attn writes gT

  k_prep<<<(788480 + 255) / 256, 256, 0, stream>>>(kw, vw, qpw, pw, ab, bidx, noff,
                                                   kwb, vwb, qwb, pwb, bxp);

  // transpose + fused depthwise q-conv
  k_transpose_dwq<<<dim3(6, BATCH), 256, 0, stream>>>(x, xbT, qlw, qlb, qlT);

  // k: A=xbT[100352][384] (m=j), B=kwb[128][384] (n=ch) -> kTh[b][h][196][16]
  k_gemm_flat<0, false, NPOS><<<784, 256, 0, stream>>>(
      xbT, kwb, kTm, kb, kbs, kbt, DIM, 784, NH_KD, 0);
  // v: A=vwb[512][384] (m=ch), B=xbT (n=j) -> v4m[b][512][196]
  k_gemm_flat<NPOS, false, 0><<<3136, 256, 0, stream>>>(
      vwb, xbT, v4m, vb, vbs, vbt, DIM, 4, 0, (long)DH * NPOS);
  // q: A=qlT[25088][384] (m=j), B=qwb (n=ch) -> qTh[b][h][49][16]
  k_gemm_flat<0, false, N2><<<196, 256, 0, stream>>>(
      qlT, qwb, qTm, qpb, qbs, qbt, DIM, 196, NH_KD, 0);

  k_dwconv_v<<<dim3(8, BATCH), 256, 0, stream>>>(v4m, vlw, vlb, vls, vlt_in, vlTm);
  k_attn_mfma<<<dim3(NUM_HEADS, BATCH), 256, 0, stream>>>(qTm, kTm, v4m, bxp, vlTm, gTm);

  // p: A=pwb[768][512] (m=ch), B=gTm[25088][512] (n=j) -> d_out[b][768][49] f32
  k_gemm_flat<N2, true, 0><<<1176, 256, 0, stream>>>(
      pwb, gTm, d_out, pb, pbs, pbt, DH, 6, 0, (long)OUT_DIM * N2);
}

// Round 21
// 363.438 us; speedup vs baseline: 1.1046x; 1.1046x over previous
//
#include <hip/hip_runtime.h>
#include <math.h>

#define DIM 384
#define NUM_HEADS 8
#define RES 14
#define RES2 7
#define NPOS 196
#define N2 49
#define DHEAD 64
#define NH_KD 128
#define DH 512
#define OUT_DIM 768
#define BATCH 512
#define SCALE_Q 0.25f
#define LOG2E 1.4426950408889634f
#define SCALE2 (SCALE_Q * LOG2E)

typedef unsigned short u16;
typedef short s16x8 __attribute__((ext_vector_type(8)));
typedef short s16x4 __attribute__((ext_vector_type(4)));
typedef float f32x4 __attribute__((ext_vector_type(4)));
typedef unsigned int u32x2 __attribute__((ext_vector_type(2)));

__device__ __forceinline__ float bf2f(u16 u) {
  union { unsigned int i; float f; } v; v.i = ((unsigned int)u) << 16; return v.f;
}
__device__ __forceinline__ u16 f2bf(float f) {
  union { unsigned int i; float f; } v; v.f = f;
  unsigned int r = v.i + 0x7fffu + ((v.i >> 16) & 1u);
  return (u16)(r >> 16);
}

// gelu exact-erf via A&S 7.1.26 poly (|err|<=1.5e-7; p(1)=1 so erf(0)=0 exactly)
__device__ __forceinline__ float gelu_f(float x) {
  float z = x * 0.70710678118f;
  float az = fabsf(z);
  float t = __builtin_amdgcn_rcpf(1.f + 0.3275911f * az);
  float p = ((((1.061405429f * t - 1.453152027f) * t + 1.421413741f) * t
              - 0.284496736f) * t + 0.254829592f) * t;
  float erfv = 1.f - p * __expf(-az * az);
  erfv = copysignf(erfv, z);
  return 0.5f * x * (1.f + erfv);
}

#define GLD16(gp, lp) __builtin_amdgcn_global_load_lds( \
    (const __attribute__((address_space(1))) void*)(gp), \
    (__attribute__((address_space(3))) void*)(lp), 16, 0, 0)

// ---------- fused prep: weight casts + bias gather (bias pre-scaled by log2e) ----------
__global__ __launch_bounds__(256) void k_prep(const float* __restrict__ kw, const float* __restrict__ vw,
                                              const float* __restrict__ qw, const float* __restrict__ pw,
                                              const float* __restrict__ ab, const int* __restrict__ idxs, int noff,
                                              u16* __restrict__ kwb, u16* __restrict__ vwb,
                                              u16* __restrict__ qwb, u16* __restrict__ pwb,
                                              float* __restrict__ bxp) {
  int i = blockIdx.x * 256 + threadIdx.x;
  const int e1 = NH_KD * DIM;                // 49152
  const int e2 = e1 + DH * DIM;              // 245760
  const int e3 = e2 + NH_KD * DIM;           // 294912
  const int e4 = e3 + OUT_DIM * DH;          // 688128
  const int e5 = e4 + NUM_HEADS * N2 * 256;  // 788480
  if (i < e1) kwb[i] = f2bf(kw[i]);
  else if (i < e2) vwb[i - e1] = f2bf(vw[i - e1]);
  else if (i < e3) qwb[i - e2] = f2bf(qw[i - e2]);
  else if (i < e4) pwb[i - e3] = f2bf(pw[i - e3]);
  else if (i < e5) {
    int j = i - e4;
    int f = j & 15, c = (j >> 4) & 15;
    int m = (j >> 8) % N2, h = j / (N2 * 256);
    int n = f * 16 + c;
    bxp[j] = (n < NPOS) ? ab[h * noff + idxs[m * NPOS + n]] * LOG2E : 0.f;
  }
}

// ---------- fused transpose + depthwise dwconv_q ----------
// tileT[196 pos][70 ch] u16 (r13-verified phases 2/3); r19 paired-channel phase 1.
// NOTE (r20): do NOT add a min-blocks launch_bounds here — forcing 5/CU spilled to
// scratch (WRITE_SIZE 4x) and regressed; compiler-chosen occupancy is optimal.
__global__ __launch_bounds__(256) void k_transpose_dwq(const float* __restrict__ x, u16* __restrict__ xt,
                                                       const float* __restrict__ qlw, const float* __restrict__ qlb,
                                                       u16* __restrict__ qlt) {
  int b = blockIdx.y, c0 = blockIdx.x * 64;
  __shared__ __align__(8) u16 tileT[196 * 70];   // 27,440 B
  __shared__ float wlds2[576];                   // [tap][64 ch]
  __shared__ float blds[64];
  int tid = threadIdx.x;
  const float* xb = x + (size_t)b * DIM * NPOS;

  // phase 1: 32 ch-pairs x 49 f32x4 chunks; both streams coalesced, packed b32 writes
  for (int idx = tid; idx < 32 * 49; idx += 256) {
    int chp = idx / 49, p4 = idx - chp * 49;
    const float* base = xb + (size_t)(c0 + 2 * chp) * NPOS + p4 * 4;
    f32x4 a  = *(const f32x4*)(base);
    f32x4 bv = *(const f32x4*)(base + NPOS);
#pragma unroll
    for (int j = 0; j < 4; j++) {
      uint pk = (uint)f2bf(a[j]) | ((uint)f2bf(bv[j]) << 16);
      *(uint*)&tileT[(p4 * 4 + j) * 70 + 2 * chp] = pk;
    }
  }
  for (int i = tid; i < 576; i += 256) {
    int c = i / 9, t = i % 9;
    wlds2[t * 64 + c] = qlw[(size_t)(c0 + c) * 9 + t];
  }
  if (tid < 64) blds[tid] = qlb[c0 + tid];
  __syncthreads();

  // phase 2: xbT write, 8 channels per lane, 16B vector stores
  u16* xtb = xt + (size_t)b * NPOS * DIM + c0;
  for (int idx = tid; idx < NPOS * 8; idx += 256) {
    int n = idx >> 3, g = (idx & 7) << 3;
    s16x8 val;
    ((uint*)&val)[0] = *(const uint*)&tileT[n * 70 + g];
    ((uint*)&val)[1] = *(const uint*)&tileT[n * 70 + g + 2];
    ((uint*)&val)[2] = *(const uint*)&tileT[n * 70 + g + 4];
    ((uint*)&val)[3] = *(const uint*)&tileT[n * 70 + g + 6];
    *(s16x8*)(xtb + (size_t)n * DIM + g) = val;
  }
  // phase 3: dwconv, 2 channels per lane, packed 4B stores
  u16* qb = qlt + (size_t)b * N2 * DIM + c0;
  for (int idx = tid; idx < N2 * 32; idx += 256) {
    int cp = idx & 31, n2 = idx >> 5;
    int c = cp << 1;
    int r = n2 / RES2, s = n2 % RES2;
    uint rv = *(const uint*)&tileT[((2 * r) * RES + 2 * s) * 70 + c];
    float a0 = blds[c]     + bf2f((u16)(rv & 0xffff));
    float a1 = blds[c + 1] + bf2f((u16)(rv >> 16));
#pragma unroll
    for (int dy = 0; dy < 3; dy++) {
      int ry = 2 * r - 1 + dy;
      if (ry < 0 || ry >= RES) continue;
#pragma unroll
      for (int dx = 0; dx < 3; dx++) {
        int sx = 2 * s - 1 + dx;
        if (sx < 0 || sx >= RES) continue;
        uint tv = *(const uint*)&tileT[(ry * RES + sx) * 70 + c];
        int t = dy * 3 + dx;
        a0 += wlds2[t * 64 + c]     * bf2f((u16)(tv & 0xffff));
        a1 += wlds2[t * 64 + c + 1] * bf2f((u16)(tv >> 16));
      }
    }
    uint outp = (uint)f2bf(a0) | ((uint)f2bf(a1) << 16);
    *(uint*)(qb + (size_t)n2 * DIM + c) = outp;
  }
}

// ---------- flattened GEMM: C = A[M][K] x B[N][K]^T, both K-contiguous bf16 ----------
// 128x128 tile, BK=64 (two 32-K halves, one barrier per 64-K), GLD16 staging both operands.
// Source pre-swizzle (m173/rule21): lane fetches global granule (l&3)^((l>>3)&3);
// frag reads un-swizzle with rg8 = ((l>>4)^((l>>1)&3))*8 -> conflict-free both sides.
// SPLN>0: out[(n/SPLN)*bstride + m*SPLN + n%SPLN] (ch=m), honors F32OUT.
// HBLK>0: head-blocked output [b][h=n>>4][pos=m%HBLK][n&15] (ch=n).
// NOTE (r10/r11): do NOT merge these GEMMs — L2 thrash. NOTE (r15): do NOT read A
// direct-from-global in-loop — scattered 16B reads stall the MFMA chain (87->128 us).
template <int SPLN, bool F32OUT, int HBLK>
__global__ __launch_bounds__(256) void k_gemm_flat(
    const u16* __restrict__ A, const u16* __restrict__ B, void* __restrict__ C,
    const float* __restrict__ cb, const float* __restrict__ bns, const float* __restrict__ bnt,
    int K, int NMT, int ldc, long bstride) {
  __shared__ __align__(16) u16 a_lds[2 * 128 * 32];
  __shared__ __align__(16) u16 b_lds[2 * 128 * 32];
  int nwg = gridDim.x, bx = blockIdx.x;
  int wg = ((nwg & 7) == 0) ? ((bx & 7) * (nwg >> 3) + (bx >> 3)) : bx;  // XCD-bijective
  int mt = wg % NMT, nt = wg / NMT;                                      // m fastest: j-tile shared on-XCD
  int m0 = mt * 128, n0 = nt * 128;
  int tid = threadIdx.x, w = tid >> 6, l = tid & 63;

  int srow = l >> 2;
  int scol = ((l & 3) ^ ((l >> 3) & 3)) * 8;   // pre-swizzled source granule
  const u16* asrc[2]; const u16* bsrc[2];
#pragma unroll
  for (int c = 0; c < 2; c++) {
    int chunk = w * 2 + c;
    asrc[c] = A + (size_t)(m0 + chunk * 16 + srow) * K + scol;
    bsrc[c] = B + (size_t)(n0 + chunk * 16 + srow) * K + scol;
  }
  char* adst = (char*)a_lds + (w * 2) * 1024 + l * 16;
  char* bdst = (char*)b_lds + (w * 2) * 1024 + l * 16;

  f32x4 acc[4][4];
#pragma unroll
  for (int i = 0; i < 4; i++)
#pragma unroll
    for (int j = 0; j < 4; j++) acc[i][j] = (f32x4){0.f, 0.f, 0.f, 0.f};

  int wm = w >> 1, wn = w & 1;
  int rg8 = ((l >> 4) ^ ((l >> 1) & 3)) * 8;   // un-swizzling read granule
  int arow = wm * 64 + (l & 15);
  int brow = wn * 64 + (l & 15);

  for (int kk = 0; kk < K; kk += 64) {
#pragma unroll
    for (int c = 0; c < 2; c++) {
      GLD16(asrc[c] + kk,      adst + c * 1024);
      GLD16(asrc[c] + kk + 32, adst + 8192 + c * 1024);
      GLD16(bsrc[c] + kk,      bdst + c * 1024);
      GLD16(bsrc[c] + kk + 32, bdst + 8192 + c * 1024);
    }
    __syncthreads();                 // compiler drains vmcnt before barrier
#pragma unroll
    for (int hf = 0; hf < 2; hf++) {
      const u16* ah = a_lds + hf * (128 * 32);
      const u16* bh = b_lds + hf * (128 * 32);
      s16x8 af[4], bf[4];
#pragma unroll
      for (int i = 0; i < 4; i++) {
        af[i] = *(const s16x8*)(&ah[(arow + i * 16) * 32 + rg8]);
        bf[i] = *(const s16x8*)(&bh[(brow + i * 16) * 32 + rg8]);
      }
#pragma unroll
      for (int i = 0; i < 4; i++)
#pragma unroll
        for (int j = 0; j < 4; j++)
          acc[i][j] = __builtin_amdgcn_mfma_f32_16x16x32_bf16(af[i], bf[j], acc[i][j], 0, 0, 0);
    }
    __syncthreads();
  }

  int ncol = l & 15, mq = (l >> 4) * 4;
#pragma unroll
  for (int i = 0; i < 4; i++) {
#pragma unroll
    for (int j = 0; j < 4; j++) {
      int n = n0 + wn * 64 + j * 16 + ncol;
#pragma unroll
      for (int r = 0; r < 4; r++) {
        int m = m0 + wm * 64 + i * 16 + mq + r;
        int ch = SPLN ? m : n;
        float val = acc[i][j][r] * bns[ch] + (cb[ch] * bns[ch] + bnt[ch]);
        size_t o;
        if (HBLK) {
          int bb = m / HBLK, pos = m - bb * HBLK;
          o = (((size_t)bb * NUM_HEADS + (n >> 4)) * HBLK + pos) * 16 + (n & 15);
        } else if (SPLN) {
          o = (size_t)(n / SPLN) * bstride + (size_t)m * SPLN + (n % SPLN);
        } else {
          o = (size_t)m * ldc + n;
        }
        if (F32OUT) ((float*)C)[o] = val;
        else        ((u16*)C)[o] = f2bf(val);
      }
    }
  }
}

// ---------- v_local = BN(dwconv_s2(v4) + b) -> vlT (bf16 [b][49][512]) ----------
__global__ __launch_bounds__(256) void k_dwconv_v(const u16* __restrict__ v4, const float* __restrict__ w,
    const float* __restrict__ bias, const float* __restrict__ bns, const float* __restrict__ bnt,
    u16* __restrict__ vlt) {
  int b = blockIdx.y, ct = blockIdx.x;
  __shared__ __align__(8) u16 tile[64][196];
  int tid = threadIdx.x, wave = tid >> 6, lane = tid & 63;
  const u16* vbp = v4 + ((size_t)b * DH + ct * 64) * NPOS;
  for (int r = wave; r < 64; r += 4) {
    const u32x2* grow = (const u32x2*)(vbp + (size_t)r * NPOS);
    if (lane < 49) ((u32x2*)&tile[r][0])[lane] = grow[lane];
  }
  __syncthreads();
  for (int idx = tid; idx < 64 * N2; idx += 256) {
    int cl = idx & 63, n2 = idx >> 6;
    int ch = ct * 64 + cl;
    int r = n2 / RES2, s = n2 % RES2;
    float acc = bias[ch];
#pragma unroll
    for (int dy = 0; dy < 3; dy++) {
      int ry = 2 * r - 1 + dy;
      if (ry < 0 || ry >= RES) continue;
#pragma unroll
      for (int dx = 0; dx < 3; dx++) {
        int sx = 2 * s - 1 + dx;
        if (sx < 0 || sx >= RES) continue;
        acc += w[ch * 9 + dy * 3 + dx] * bf2f(tile[cl][ry * RES + sx]);
      }
    }
    vlt[((size_t)b * N2 + n2) * DH + ch] = f2bf(acc * bns[ch] + bnt[ch]);
  }
}

// ---------- MFMA attention per (b,h), LDS = p_lds only (29.7 KB) ----------
// Q/K in head-blocked layouts ([b][h][pos][16]) -> wave frag loads are one contiguous
// 512B block. exp2-folded softmax (scale/bias pre-multiplied by log2e).
// V direct from v4 ([b][512][196] = B-operand rows) as 2x8B. o_lds overlaps p_lds.
// NOTE (r20): min-blocks=5 here spilled to scratch (WRITE_SIZE 25->107 MB, 85->119 us);
// keep (256,4).
__global__ __launch_bounds__(256, 4) void k_attn_mfma(const u16* __restrict__ qTh, const u16* __restrict__ kTh,
    const u16* __restrict__ v4, const float* __restrict__ bxp, const u16* __restrict__ vlT,
    u16* __restrict__ gT) {
  int h = blockIdx.x, b = blockIdx.y;
  __shared__ __align__(16) u16 p_lds[64 * 232];   // 29,696 B
  float* o_lds = (float*)p_lds;                   // overlap (barrier-protected)
  int tid = threadIdx.x, w = tid >> 6, l = tid & 63;
  int part = l >> 4, row16 = l & 15;
  int mbase = w * 16 + part * 4;
  int ncol = l & 15;

  for (int idx = tid; idx < 64 * 8; idx += 256)
    ((uint*)&p_lds[(idx >> 3) * 232])[104 + (idx & 7)] = 0;

  // Q frag: qTh[b][h][pos][16], contiguous 512B per wave-frag (rows >=49 -> masked garbage)
  const u16* qbase = qTh + ((size_t)(b * NUM_HEADS + h) * N2) * 16;
  s16x8 af = (s16x8){0, 0, 0, 0, 0, 0, 0, 0};
  if (part < 2)
    af = *(const s16x8*)(qbase + (w * 16 + row16) * 16 + part * 8);

  // K frags: kTh[b][h][pos][16] (rows >=196 -> masked garbage)
  const u16* kbase = kTh + ((size_t)(b * NUM_HEADS + h) * NPOS) * 16 + part * 8;
  f32x4 s[13];
#pragma unroll
  for (int f = 0; f < 13; f++) {
    s16x8 bf = (s16x8){0, 0, 0, 0, 0, 0, 0, 0};
    if (part < 2)
      bf = *(const s16x8*)(kbase + (size_t)(f * 16 + row16) * 16);
    s[f] = __builtin_amdgcn_mfma_f32_16x16x32_bf16(af, bf, (f32x4){0.f, 0.f, 0.f, 0.f}, 0, 0, 0);
  }

  const u16* vbase = v4 + ((size_t)b * DH + h * DHEAD) * NPOS;
  int vd = l & 15, vq8 = part * 8;
  auto VLOAD = [&](int f, int kk) {
    const u16* p = vbase + (size_t)(f * 16 + vd) * NPOS + kk + vq8;
    s16x8 r;
    ((u32x2*)&r)[0] = *(const u32x2*)(p);
    ((u32x2*)&r)[1] = *(const u32x2*)(p + 4);
    return r;
  };
  s16x8 vb0[4];
#pragma unroll
  for (int f = 0; f < 4; f++) vb0[f] = VLOAD(f, 0);

  // scale+bias (log2e-folded) + mask
#pragma unroll
  for (int q = 0; q < 4; q++) {
    f32x4 bqr[4];
#pragma unroll
    for (int r = 0; r < 4; r++) {
      int mm = mbase + r; if (mm > N2 - 1) mm = N2 - 1;
      bqr[r] = *(const f32x4*)(bxp + (((size_t)h * N2 + mm) * 16 + ncol) * 16 + q * 4);
    }
#pragma unroll
    for (int ff = 0; ff < 4; ff++) {
      int f = q * 4 + ff;
      if (f < 13) {
        int n = f * 16 + ncol;
#pragma unroll
        for (int r = 0; r < 4; r++) {
          int m = mbase + r;
          s[f][r] = (m < N2 && n < NPOS) ? s[f][r] * SCALE2 + bqr[r][ff] : -1e30f;
        }
      }
    }
  }
  // softmax in base-2: rows live in 16-lane groups -> shfl_xor 1,2,4,8
#pragma unroll
  for (int r = 0; r < 4; r++) {
    float mx = s[0][r];
#pragma unroll
    for (int f = 1; f < 13; f++) mx = fmaxf(mx, s[f][r]);
    mx = fmaxf(mx, __shfl_xor(mx, 1)); mx = fmaxf(mx, __shfl_xor(mx, 2));
    mx = fmaxf(mx, __shfl_xor(mx, 4)); mx = fmaxf(mx, __shfl_xor(mx, 8));
    float sum = 0.f;
#pragma unroll
    for (int f = 0; f < 13; f++) { s[f][r] = exp2f(s[f][r] - mx); sum += s[f][r]; }
    sum += __shfl_xor(sum, 1); sum += __shfl_xor(sum, 2);
    sum += __shfl_xor(sum, 4); sum += __shfl_xor(sum, 8);
    float inv = 1.f / sum;
#pragma unroll
    for (int f = 0; f < 13; f++) s[f][r] *= inv;
  }
#pragma unroll
  for (int f = 0; f < 13; f++) {
    int n = f * 16 + ncol;
#pragma unroll
    for (int r = 0; r < 4; r++)
      p_lds[(mbase + r) * 232 + n] = f2bf(s[f][r]);
  }
  __syncthreads();

  f32x4 o[4];
#pragma unroll
  for (int f = 0; f < 4; f++) o[f] = (f32x4){0.f, 0.f, 0.f, 0.f};
#pragma unroll
  for (int t = 0; t < 7; t++) {
    int kk = t * 32;
    s16x8 vn[4];
    if (t < 6) {
#pragma unroll
      for (int f = 0; f < 4; f++) vn[f] = VLOAD(f, kk + 32);
    }
    s16x8 pa = *(const s16x8*)(&p_lds[(w * 16 + row16) * 232 + kk + part * 8]);
#pragma unroll
    for (int f = 0; f < 4; f++)
      o[f] = __builtin_amdgcn_mfma_f32_16x16x32_bf16(pa, vb0[f], o[f], 0, 0, 0);
    if (t < 6) {
#pragma unroll
      for (int f = 0; f < 4; f++) vb0[f] = vn[f];
    }
  }
  __syncthreads();

#pragma unroll
  for (int f = 0; f < 4; f++)
#pragma unroll
    for (int r = 0; r < 4; r++) {
      int m = mbase + r;
      if (m < N2) o_lds[m * 68 + f * 16 + ncol] = o[f][r];
    }
  __syncthreads();

  for (int idx = tid; idx < N2 * 16; idx += 256) {
    int row = idx >> 4, c4 = (idx & 15) << 2;
    f32x4 ov = *(const f32x4*)(&o_lds[row * 68 + c4]);
    size_t go = ((size_t)b * N2 + row) * DH + h * DHEAD + c4;
    s16x4 vv = *(const s16x4*)(vlT + go);
    s16x4 outv;
#pragma unroll
    for (int e = 0; e < 4; e++) {
      float xv = ov[e] + bf2f((u16)vv[e]);
      outv[e] = (short)f2bf(gelu_f(xv));
    }
    *(s16x4*)(gT + go) = outv;
  }
}

extern "C" void kernel_launch(void* const* d_in, const int* in_sizes, int n_in,
                              void* d_out, int out_size, void* d_ws, size_t ws_size,
                              hipStream_t stream) {
  const float* x   = (const float*)d_in[0];
  const float* qlw = (const float*)d_in[1];
  const float* qlb = (const float*)d_in[2];
  const float* qpw = (const float*)d_in[3];
  const float* qpb = (const float*)d_in[4];
  const float* qbs = (const float*)d_in[5];
  const float* qbt = (const float*)d_in[6];
  const float* kw  = (const float*)d_in[7];
  const float* kb  = (const float*)d_in[8];
  const float* kbs = (const float*)d_in[9];
  const float* kbt = (const float*)d_in[10];
  const float* vw  = (const float*)d_in[11];
  const float* vb  = (const float*)d_in[12];
  const float* vbs = (const float*)d_in[13];
  const float* vbt = (const float*)d_in[14];
  const float* vlw = (const float*)d_in[15];
  const float* vlb = (const float*)d_in[16];
  const float* vls = (const float*)d_in[17];
  const float* vlt_in = (const float*)d_in[18];
  const float* pw  = (const float*)d_in[19];
  const float* pb  = (const float*)d_in[20];
  const float* pbs = (const float*)d_in[21];
  const float* pbt = (const float*)d_in[22];
  const float* ab  = (const float*)d_in[23];
  const int*   bidx = (const int*)d_in[24];
  int noff = in_sizes[23] / NUM_HEADS;

  char* ws = (char*)d_ws;
  size_t off = 0;
  auto alloc = [&](size_t bytes) { char* p = ws + off; off += (bytes + 255) & ~(size_t)255; return p; };
  u16* xbT = (u16*)alloc((size_t)BATCH * NPOS * DIM * 2);      // 77.1 MB (aliased by gT later)
  u16* kTm = (u16*)alloc((size_t)BATCH * NPOS * NH_KD * 2);    // 25.7 MB (head-blocked [b][h][196][16])
  u16* qlT = (u16*)alloc((size_t)BATCH * N2 * DIM * 2);        // 19.3 MB
  u16* qTm = (u16*)alloc((size_t)BATCH * N2 * NH_KD * 2);      //  6.4 MB (head-blocked [b][h][49][16])
  u16* v4m = (u16*)alloc((size_t)BATCH * DH * NPOS * 2);       // 102.8 MB
  u16* vlTm = (u16*)alloc((size_t)BATCH * N2 * DH * 2);        // 25.7 MB  (absorbs attn's OOB V reads)
  float* bxp = (float*)alloc((size_t)NUM_HEADS * N2 * 16 * 16 * 4);  // 0.8 MB
  u16* kwb = (u16*)alloc((size_t)NH_KD * DIM * 2);
  u16* vwb = (u16*)alloc((size_t)DH * DIM * 2);
  u16* qwb = (u16*)alloc((size_t)NH_KD * DIM * 2);
  u16* pwb = (u16*)alloc((size_t)OUT_DIM * DH * 2);
  u16* gTm = xbT;  // alias: all xbT readers complete before k_attn writes gT

  k_prep<<<(788480 + 255) / 256, 256, 0, stream>>>(kw, vw, qpw, pw, ab, bidx, noff,
                                                   kwb, vwb, qwb, pwb, bxp);

  // transpose + fused depthwise q-conv
  k_transpose_dwq<<<dim3(6, BATCH), 256, 0, stream>>>(x, xbT, qlw, qlb, qlT);

  // k: A=xbT[100352][384] (m=j), B=kwb[128][384] (n=ch) -> kTh[b][h][196][16]
  k_gemm_flat<0, false, NPOS><<<784, 256, 0, stream>>>(
      xbT, kwb, kTm, kb, kbs, kbt, DIM, 784, NH_KD, 0);
  // v: A=vwb[512][384] (m=ch), B=xbT (n=j) -> v4m[b][512][196]
  k_gemm_flat<NPOS, false, 0><<<3136, 256, 0, stream>>>(
      vwb, xbT, v4m, vb, vbs, vbt, DIM, 4, 0, (long)DH * NPOS);
  // q: A=qlT[25088][384] (m=j), B=qwb (n=ch) -> qTh[b][h][49][16]
  k_gemm_flat<0, false, N2><<<196, 256, 0, stream>>>(
      qlT, qwb, qTm, qpb, qbs, qbt, DIM, 196, NH_KD, 0);

  k_dwconv_v<<<dim3(8, BATCH), 256, 0, stream>>>(v4m, vlw, vlb, vls, vlt_in, vlTm);
  k_attn_mfma<<<dim3(NUM_HEADS, BATCH), 256, 0, stream>>>(qTm, kTm, v4m, bxp, vlTm, gTm);

  // p: A=pwb[768][512] (m=ch), B=gTm[25088][512] (n=j) -> d_out[b][768][49] f32
  k_gemm_flat<N2, true, 0><<<1176, 256, 0, stream>>>(
      pwb, gTm, d_out, pb, pbs, pbt, DH, 6, 0, (long)OUT_DIM * N2);
}